// Round 4
// baseline (202.585 us; speedup 1.0000x reference)
//
#include <hip/hip_runtime.h>
#include <math.h>

#define W 512
#define H 512
#define NPIX (W*H)
#define RAD 10
#define KS 21
#define CRF_EPS 1e-4f

// fused-tile geometry: TX x TY outputs per block, halo RAD each side
#define TX 32
#define TY 16
#define CIN (TX + 2*RAD)   // 52 input cols
#define RIN (TY + 2*RAD)   // 36 input rows
#define GX (W / TX)        // 16
#define GY (H / TY)        // 32
#define NBLK (GX*GY)       // 512 blocks = 2/CU
#define NVT (CIN * 4)      // 208 V-phase threads (4 output rows each)

struct W21 { float w[KS]; };

__device__ __forceinline__ float4 f4(float x, float y, float z, float w_) {
    return make_float4(x, y, z, w_);
}
__device__ __forceinline__ float4 fma4(float s, float4 a, float4 acc) {
    acc.x = fmaf(s, a.x, acc.x); acc.y = fmaf(s, a.y, acc.y);
    acc.z = fmaf(s, a.z, acc.z); acc.w = fmaf(s, a.w, acc.w);
    return acc;
}
// XCD swizzle: consecutive HW block ids round-robin across 8 XCDs; give each
// XCD a contiguous LOGICAL tile range so geometric neighbors share an L2.
__device__ __forceinline__ int swz(int b, int N) {
    return (b & 7) * (N >> 3) + (b >> 3);
}

// ---- setup kernels ----

__global__ __launch_bounds__(512) void k_tables(W21 wg, W21 wu, float* Sg, float* Su) {
    int x = threadIdx.x;
    float sg = 0.f, su = 0.f;
    #pragma unroll
    for (int d = -RAD; d <= RAD; ++d) {
        int xx = x + d;
        if (xx >= 0 && xx < W) { sg += wg.w[d + RAD]; su += wu.w[d + RAD]; }
    }
    Sg[x] = sg; Su[x] = su;
}

__global__ __launch_bounds__(256) void k_init(const float* __restrict__ img,
        const float4* __restrict__ unary, float* __restrict__ gray,
        float4* __restrict__ Q) {
    int b = swz(blockIdx.x, NPIX / 256);
    int p = b * 256 + threadIdx.x;
    float r = img[3 * p], g = img[3 * p + 1], bch = img[3 * p + 2];
    gray[p] = 0.2989f * r + 0.5870f * g + 0.1140f * bch;
    float4 u = unary[p];
    float mn = fminf(fminf(u.x, u.y), fminf(u.z, u.w));
    float ex = expf(mn - u.x), ey = expf(mn - u.y), ez = expf(mn - u.z), ew = expf(mn - u.w);
    float inv = 1.f / (ex + ey + ez + ew);
    Q[p] = f4(ex * inv, ey * inv, ez * inv, ew * inv);
}

// fused 2D conv of {gray, gray^2} -> mean_I, inv_var, a1b1
__global__ __launch_bounds__(256) void k_s1(const float* __restrict__ gray,
        const float* __restrict__ Su, float* __restrict__ mean_I,
        float* __restrict__ inv_var, float2* __restrict__ a1b1,
        W21 wu, float c0u) {
    __shared__ float  sg[RIN][CIN];
    __shared__ float2 ii[TY][CIN];
    int L = swz(blockIdx.x, NBLK);
    int x0 = (L & (GX - 1)) * TX, y0 = (L >> 4) * TY;
    int t = threadIdx.x;
    for (int i = t; i < RIN * CIN; i += 256) {
        int r = i / CIN, c = i - r * CIN;
        int gx = x0 + c - RAD, gy = y0 + r - RAD;
        float g = 0.f;
        if ((unsigned)gx < W && (unsigned)gy < H) g = gray[gy * W + gx];
        sg[r][c] = g;
    }
    __syncthreads();
    if (t < NVT) {
        int c = t % CIN, rg = t / CIN, r0 = rg * 4;
        float2 acc[4];
        #pragma unroll
        for (int j = 0; j < 4; ++j) acc[j] = make_float2(0.f, 0.f);
        #pragma unroll
        for (int s = 0; s < 24; ++s) {
            float g = sg[r0 + s][c];
            #pragma unroll
            for (int j = 0; j < 4; ++j) {
                int d = s - j;
                if (d >= 0 && d <= 20) {
                    float wg_ = wu.w[d] * g;
                    acc[j].x += wg_;
                    acc[j].y = fmaf(wg_, g, acc[j].y);
                }
            }
        }
        #pragma unroll
        for (int j = 0; j < 4; ++j) ii[r0 + j][c] = acc[j];
    }
    __syncthreads();
    if (t < 128) {
        int row = t >> 3, c0 = (t & 7) * 4;
        float2 A[4];
        #pragma unroll
        for (int j = 0; j < 4; ++j) A[j] = make_float2(0.f, 0.f);
        #pragma unroll
        for (int s = 0; s < 24; ++s) {
            float2 v = ii[row][c0 + s];
            #pragma unroll
            for (int j = 0; j < 4; ++j) {
                int d = s - j;
                if (d >= 0 && d <= 20) {
                    A[j].x = fmaf(wu.w[d], v.x, A[j].x);
                    A[j].y = fmaf(wu.w[d], v.y, A[j].y);
                }
            }
        }
        int py = y0 + row;
        float Suy = Su[py];
        #pragma unroll
        for (int j = 0; j < 4; ++j) {
            int px = x0 + c0 + j;
            int p = py * W + px;
            float gc = sg[row + RAD][c0 + j + RAD];
            float mI = A[j].x - c0u * gc;
            float mII = A[j].y - c0u * gc * gc;
            float iv = 1.f / ((mII - mI * mI) + CRF_EPS);
            float N = Su[px] * Suy - c0u;
            float av = mI * (1.f - N) * iv;
            float bv = N - av * mI;
            mean_I[p] = mI; inv_var[p] = iv; a1b1[p] = make_float2(av, bv);
        }
    }
}

// fused 2D conv of a1b1 -> inv_bilateral_norm
__global__ __launch_bounds__(256) void k_s2(const float2* __restrict__ a1b1,
        const float* __restrict__ gray, float* __restrict__ inv_bn,
        W21 wu, float c0u) {
    __shared__ float2 s2[RIN][CIN];
    __shared__ float2 ii[TY][CIN];
    int L = swz(blockIdx.x, NBLK);
    int x0 = (L & (GX - 1)) * TX, y0 = (L >> 4) * TY;
    int t = threadIdx.x;
    for (int i = t; i < RIN * CIN; i += 256) {
        int r = i / CIN, c = i - r * CIN;
        int gx = x0 + c - RAD, gy = y0 + r - RAD;
        float2 v = make_float2(0.f, 0.f);
        if ((unsigned)gx < W && (unsigned)gy < H) v = a1b1[gy * W + gx];
        s2[r][c] = v;
    }
    __syncthreads();
    if (t < NVT) {
        int c = t % CIN, rg = t / CIN, r0 = rg * 4;
        float2 acc[4];
        #pragma unroll
        for (int j = 0; j < 4; ++j) acc[j] = make_float2(0.f, 0.f);
        #pragma unroll
        for (int s = 0; s < 24; ++s) {
            float2 v = s2[r0 + s][c];
            #pragma unroll
            for (int j = 0; j < 4; ++j) {
                int d = s - j;
                if (d >= 0 && d <= 20) {
                    acc[j].x = fmaf(wu.w[d], v.x, acc[j].x);
                    acc[j].y = fmaf(wu.w[d], v.y, acc[j].y);
                }
            }
        }
        #pragma unroll
        for (int j = 0; j < 4; ++j) ii[r0 + j][c] = acc[j];
    }
    __syncthreads();
    if (t < 128) {
        int row = t >> 3, c0 = (t & 7) * 4;
        float2 A[4];
        #pragma unroll
        for (int j = 0; j < 4; ++j) A[j] = make_float2(0.f, 0.f);
        #pragma unroll
        for (int s = 0; s < 24; ++s) {
            float2 v = ii[row][c0 + s];
            #pragma unroll
            for (int j = 0; j < 4; ++j) {
                int d = s - j;
                if (d >= 0 && d <= 20) {
                    A[j].x = fmaf(wu.w[d], v.x, A[j].x);
                    A[j].y = fmaf(wu.w[d], v.y, A[j].y);
                }
            }
        }
        int py = y0 + row;
        #pragma unroll
        for (int j = 0; j < 4; ++j) {
            int px = x0 + c0 + j;
            int p = py * W + px;
            float2 cen = s2[row + RAD][c0 + j + RAD];
            float va = A[j].x - c0u * cen.x;
            float vb = A[j].y - c0u * cen.y;
            inv_bn[p] = 1.f / (va * gray[p] + vb);
        }
    }
}

// ---- iteration kernels ----

// F1: Q -> a, b, partial.  V-conv (3 planes, 4 rows/thread) into LDS,
// H-conv (4 cols/thread), pointwise.
__global__ __launch_bounds__(256) void k_f1(const float4* __restrict__ Q,
        const float* __restrict__ gray, const float* __restrict__ mean_I,
        const float* __restrict__ inv_var, const float* __restrict__ Sg,
        const float4* __restrict__ unary, float4* __restrict__ a_out,
        float4* __restrict__ b_out, float4* __restrict__ partial,
        W21 wg, W21 wu, float c0g, float c0u) {
    __shared__ float4 sQ[RIN][CIN];   // 29.9 KB
    __shared__ float  sG[RIN][CIN];   //  7.3 KB
    __shared__ float4 i0[TY][CIN];    // 13.3 KB  gauss(Q) V-pass
    __shared__ float4 i1[TY][CIN];    // 13.3 KB  guided(Q) V-pass
    __shared__ float4 i2[TY][CIN];    // 13.3 KB  guided(gray*Q) V-pass
    int L = swz(blockIdx.x, NBLK);
    int x0 = (L & (GX - 1)) * TX, y0 = (L >> 4) * TY;
    int t = threadIdx.x;
    for (int i = t; i < RIN * CIN; i += 256) {
        int r = i / CIN, c = i - r * CIN;
        int gx = x0 + c - RAD, gy = y0 + r - RAD;
        float4 q = f4(0.f, 0.f, 0.f, 0.f); float g = 0.f;
        if ((unsigned)gx < W && (unsigned)gy < H) {
            int p = gy * W + gx; q = Q[p]; g = gray[p];
        }
        sQ[r][c] = q; sG[r][c] = g;
    }
    __syncthreads();
    if (t < NVT) {
        int c = t % CIN, rg = t / CIN, r0 = rg * 4;
        float4 a0[4], a1[4], a2[4];
        #pragma unroll
        for (int j = 0; j < 4; ++j) { a0[j] = f4(0,0,0,0); a1[j] = a0[j]; a2[j] = a0[j]; }
        #pragma unroll
        for (int s = 0; s < 24; ++s) {
            float4 q = sQ[r0 + s][c]; float g = sG[r0 + s][c];
            float4 gq = f4(g * q.x, g * q.y, g * q.z, g * q.w);
            #pragma unroll
            for (int j = 0; j < 4; ++j) {
                int d = s - j;
                if (d >= 0 && d <= 20) {
                    a0[j] = fma4(wg.w[d], q, a0[j]);
                    a1[j] = fma4(wu.w[d], q, a1[j]);
                    a2[j] = fma4(wu.w[d], gq, a2[j]);
                }
            }
        }
        #pragma unroll
        for (int j = 0; j < 4; ++j) {
            i0[r0 + j][c] = a0[j]; i1[r0 + j][c] = a1[j]; i2[r0 + j][c] = a2[j];
        }
    }
    __syncthreads();
    if (t < 128) {
        int row = t >> 3, c0 = (t & 7) * 4;
        float4 A0[4], A1[4], A2[4];
        #pragma unroll
        for (int j = 0; j < 4; ++j) { A0[j] = f4(0,0,0,0); A1[j] = A0[j]; A2[j] = A0[j]; }
        #pragma unroll
        for (int s = 0; s < 24; ++s) {
            float4 v0 = i0[row][c0 + s], v1 = i1[row][c0 + s], v2 = i2[row][c0 + s];
            #pragma unroll
            for (int j = 0; j < 4; ++j) {
                int d = s - j;
                if (d >= 0 && d <= 20) {
                    A0[j] = fma4(wg.w[d], v0, A0[j]);
                    A1[j] = fma4(wu.w[d], v1, A1[j]);
                    A2[j] = fma4(wu.w[d], v2, A2[j]);
                }
            }
        }
        int py = y0 + row;
        float Sgy = Sg[py];
        #pragma unroll
        for (int j = 0; j < 4; ++j) {
            int px = x0 + c0 + j;
            int p = py * W + px;
            float4 Qc = sQ[row + RAD][c0 + j + RAD];
            float gc = sG[row + RAD][c0 + j + RAD];
            float4 g4  = fma4(-c0g, Qc, A0[j]);
            float4 m4  = fma4(-c0u, Qc, A1[j]);
            float4 mi4 = fma4(-c0u * gc, Qc, A2[j]);
            float mI = mean_I[p], iv = inv_var[p];
            float4 a, b;
            a.x = (mi4.x - mI * m4.x) * iv; a.y = (mi4.y - mI * m4.y) * iv;
            a.z = (mi4.z - mI * m4.z) * iv; a.w = (mi4.w - mI * m4.w) * iv;
            b.x = m4.x - a.x * mI; b.y = m4.y - a.y * mI;
            b.z = m4.z - a.z * mI; b.w = m4.w - a.w * mI;
            float s3 = 3.f / (Sg[px] * Sgy - c0g);
            float4 u = unary[p];
            float4 part = f4(fmaf(s3, g4.x, -u.x), fmaf(s3, g4.y, -u.y),
                             fmaf(s3, g4.z, -u.z), fmaf(s3, g4.w, -u.w));
            a_out[p] = a; b_out[p] = b; partial[p] = part;
        }
    }
}

// F2: a,b -> message + softmax -> Qout.  Sequential a/b tile phases,
// 4-row V-conv, 4-col H-conv.
__global__ __launch_bounds__(256) void k_f2(const float4* __restrict__ A,
        const float4* __restrict__ B, const float4* __restrict__ partial,
        const float* __restrict__ gray, const float* __restrict__ inv_bn,
        float4* __restrict__ Qout, W21 wu, float c0u) {
    __shared__ float4 sT[RIN][CIN];   // 29.9 KB (a then b)
    __shared__ float4 ia[TY][CIN];    // 13.3 KB
    __shared__ float4 ib[TY][CIN];    // 13.3 KB
    int L = swz(blockIdx.x, NBLK);
    int x0 = (L & (GX - 1)) * TX, y0 = (L >> 4) * TY;
    int t = threadIdx.x;
    int vc = t % CIN, vrg = t / CIN, vr0 = vrg * 4;     // V map
    int row = t >> 3, c0 = (t & 7) * 4;                  // H map (t<128)
    // --- phase A ---
    for (int i = t; i < RIN * CIN; i += 256) {
        int r = i / CIN, c = i - r * CIN;
        int gx = x0 + c - RAD, gy = y0 + r - RAD;
        float4 v = f4(0.f, 0.f, 0.f, 0.f);
        if ((unsigned)gx < W && (unsigned)gy < H) v = A[gy * W + gx];
        sT[r][c] = v;
    }
    __syncthreads();
    float4 Ac[4];
    if (t < 128) {
        #pragma unroll
        for (int j = 0; j < 4; ++j) Ac[j] = sT[row + RAD][c0 + j + RAD];
    }
    if (t < NVT) {
        float4 acc[4];
        #pragma unroll
        for (int j = 0; j < 4; ++j) acc[j] = f4(0,0,0,0);
        #pragma unroll
        for (int s = 0; s < 24; ++s) {
            float4 v = sT[vr0 + s][vc];
            #pragma unroll
            for (int j = 0; j < 4; ++j) {
                int d = s - j;
                if (d >= 0 && d <= 20) acc[j] = fma4(wu.w[d], v, acc[j]);
            }
        }
        #pragma unroll
        for (int j = 0; j < 4; ++j) ia[vr0 + j][vc] = acc[j];
    }
    __syncthreads();
    // --- phase B ---
    for (int i = t; i < RIN * CIN; i += 256) {
        int r = i / CIN, c = i - r * CIN;
        int gx = x0 + c - RAD, gy = y0 + r - RAD;
        float4 v = f4(0.f, 0.f, 0.f, 0.f);
        if ((unsigned)gx < W && (unsigned)gy < H) v = B[gy * W + gx];
        sT[r][c] = v;
    }
    __syncthreads();
    if (t < NVT) {
        float4 acc[4];
        #pragma unroll
        for (int j = 0; j < 4; ++j) acc[j] = f4(0,0,0,0);
        #pragma unroll
        for (int s = 0; s < 24; ++s) {
            float4 v = sT[vr0 + s][vc];
            #pragma unroll
            for (int j = 0; j < 4; ++j) {
                int d = s - j;
                if (d >= 0 && d <= 20) acc[j] = fma4(wu.w[d], v, acc[j]);
            }
        }
        #pragma unroll
        for (int j = 0; j < 4; ++j) ib[vr0 + j][vc] = acc[j];
    }
    __syncthreads();
    // --- H-conv + message + softmax ---
    if (t < 128) {
        float4 VA[4], VB[4];
        #pragma unroll
        for (int j = 0; j < 4; ++j) { VA[j] = f4(0,0,0,0); VB[j] = VA[j]; }
        #pragma unroll
        for (int s = 0; s < 24; ++s) {
            float4 va = ia[row][c0 + s], vb = ib[row][c0 + s];
            #pragma unroll
            for (int j = 0; j < 4; ++j) {
                int d = s - j;
                if (d >= 0 && d <= 20) {
                    VA[j] = fma4(wu.w[d], va, VA[j]);
                    VB[j] = fma4(wu.w[d], vb, VB[j]);
                }
            }
        }
        int py = y0 + row;
        #pragma unroll
        for (int j = 0; j < 4; ++j) {
            int px = x0 + c0 + j;
            int p = py * W + px;
            float4 Bc = sT[row + RAD][c0 + j + RAD];
            float4 a4 = fma4(-c0u, Ac[j], VA[j]);
            float4 b4 = fma4(-c0u, Bc, VB[j]);
            float gv = gray[p];
            float ibn = 10.f * inv_bn[p];
            float4 part = partial[p];
            float lx = fmaf(fmaf(a4.x, gv, b4.x), ibn, part.x);
            float ly = fmaf(fmaf(a4.y, gv, b4.y), ibn, part.y);
            float lz = fmaf(fmaf(a4.z, gv, b4.z), ibn, part.z);
            float lw = fmaf(fmaf(a4.w, gv, b4.w), ibn, part.w);
            float m = fmaxf(fmaxf(lx, ly), fmaxf(lz, lw));
            float ex = expf(lx - m), ey = expf(ly - m), ez = expf(lz - m), ew = expf(lw - m);
            float inv = 1.f / (ex + ey + ez + ew);
            Qout[p] = f4(ex * inv, ey * inv, ez * inv, ew * inv);
        }
    }
}

// ---- host ----

static void make_w_host(double theta, W21* w, float* c0) {
    double tmp[KS], s = 0.0;
    for (int d = -RAD; d <= RAD; ++d) {
        double v = exp(-(double)(d * d) / (2.0 * theta * theta));
        tmp[d + RAD] = v; s += v;
    }
    for (int i = 0; i < KS; ++i) w->w[i] = (float)(tmp[i] / s);
    *c0 = (float)(1.0 / (s * s));   // normalized 2D center weight
}

extern "C" void kernel_launch(void* const* d_in, const int* in_sizes, int n_in,
                              void* d_out, int out_size, void* d_ws, size_t ws_size,
                              hipStream_t stream) {
    const float4* unary = (const float4*)d_in[0];
    const float* image = (const float*)d_in[1];
    float* wsf = (float*)d_ws;

    float*  gray    = wsf;
    float*  mean_I  = wsf + 262144;
    float*  inv_var = wsf + 524288;
    float2* a1b1    = (float2*)(wsf + 786432);
    float*  inv_bn  = wsf + 1310720;
    float*  Sg      = wsf + 1572864;
    float*  Su      = wsf + 1573376;
    float4* Q       = (float4*)(wsf + 1573888);
    float4* partial = (float4*)(wsf + 2622464);
    float4* a_arr   = (float4*)(wsf + 3671040);
    float4* b_arr   = (float4*)(wsf + 4719616);

    W21 wg, wu; float c0g, c0u;
    make_w_host(2.5, &wg, &c0g);
    make_w_host(10.0 / 3.0, &wu, &c0u);

    dim3 bl(256), grEl(NPIX / 256), grT(NBLK);

    k_tables<<<dim3(1), dim3(512), 0, stream>>>(wg, wu, Sg, Su);
    k_init<<<grEl, bl, 0, stream>>>(image, unary, gray, Q);
    k_s1<<<grT, bl, 0, stream>>>(gray, Su, mean_I, inv_var, a1b1, wu, c0u);
    k_s2<<<grT, bl, 0, stream>>>(a1b1, gray, inv_bn, wu, c0u);

    for (int it = 0; it < 5; ++it) {
        k_f1<<<grT, bl, 0, stream>>>((const float4*)Q, gray, mean_I, inv_var, Sg,
                                     unary, a_arr, b_arr, partial, wg, wu, c0g, c0u);
        float4* qdst = (it == 4) ? (float4*)d_out : Q;
        k_f2<<<grT, bl, 0, stream>>>(a_arr, b_arr, partial, gray, inv_bn, qdst,
                                     wu, c0u);
    }
}

// Round 5
// 173.465 us; speedup vs baseline: 1.1679x; 1.1679x over previous
//
#include <hip/hip_runtime.h>
#include <math.h>

#define W 512
#define H 512
#define NPIX (W*H)
#define RAD 10
#define KS 21
#define CRF_EPS 1e-4f

// fused-tile geometry: TX x TY outputs per block, halo RAD each side
#define TX 32
#define TY 8
#define CIN (TX + 2*RAD)   // 52 input cols
#define RIN (TY + 2*RAD)   // 28 input rows
#define GX (W / TX)        // 16
#define GY (H / TY)        // 64
#define NBLK (GX*GY)       // 1024 blocks = 4/CU
#define NVT (CIN * 4)      // 208 V-phase threads (2 output rows each)

struct W21 { float w[KS]; };

__device__ __forceinline__ float4 f4(float x, float y, float z, float w_) {
    return make_float4(x, y, z, w_);
}
__device__ __forceinline__ float4 fma4(float s, float4 a, float4 acc) {
    acc.x = fmaf(s, a.x, acc.x); acc.y = fmaf(s, a.y, acc.y);
    acc.z = fmaf(s, a.z, acc.z); acc.w = fmaf(s, a.w, acc.w);
    return acc;
}
// XCD swizzle: consecutive HW block ids round-robin across 8 XCDs; give each
// XCD a contiguous LOGICAL tile range so geometric neighbors share an L2.
__device__ __forceinline__ int swz(int b, int N) {
    return (b & 7) * (N >> 3) + (b >> 3);
}

// ---- setup ----

// gray + softmax init; blocks 0,1 (raw id) also build the 1-D border tables
__global__ __launch_bounds__(256) void k_init(const float* __restrict__ img,
        const float4* __restrict__ unary, float* __restrict__ gray,
        float4* __restrict__ Q, float* __restrict__ Sg, float* __restrict__ Su,
        W21 wg, W21 wu) {
    int t = threadIdx.x;
    if (blockIdx.x < 2) {
        int x = blockIdx.x * 256 + t;
        float sg = 0.f, su = 0.f;
        #pragma unroll
        for (int d = -RAD; d <= RAD; ++d) {
            int xx = x + d;
            if (xx >= 0 && xx < W) { sg += wg.w[d + RAD]; su += wu.w[d + RAD]; }
        }
        Sg[x] = sg; Su[x] = su;
    }
    int b = swz(blockIdx.x, NPIX / 256);
    int p = b * 256 + t;
    float r = img[3 * p], g = img[3 * p + 1], bch = img[3 * p + 2];
    gray[p] = 0.2989f * r + 0.5870f * g + 0.1140f * bch;
    float4 u = unary[p];
    float mn = fminf(fminf(u.x, u.y), fminf(u.z, u.w));
    float ex = expf(mn - u.x), ey = expf(mn - u.y), ez = expf(mn - u.z), ew = expf(mn - u.w);
    float inv = 1.f / (ex + ey + ez + ew);
    Q[p] = f4(ex * inv, ey * inv, ez * inv, ew * inv);
}

// fused 2D conv of {gray, gray^2} -> mean_I, inv_var, a1b1
__global__ __launch_bounds__(256, 4) void k_s1(const float* __restrict__ gray,
        const float* __restrict__ Su, float* __restrict__ mean_I,
        float* __restrict__ inv_var, float2* __restrict__ a1b1,
        W21 wu, float c0u) {
    __shared__ float  sg[RIN][CIN];     // 5824 B
    __shared__ float2 ii[TY][CIN];      // 3328 B
    int L = swz(blockIdx.x, NBLK);
    int x0 = (L & (GX - 1)) * TX, y0 = (L >> 4) * TY;
    int t = threadIdx.x;
    for (int i = t; i < RIN * CIN; i += 256) {
        int r = i / CIN, c = i - r * CIN;
        int gx = x0 + c - RAD, gy = y0 + r - RAD;
        float g = 0.f;
        if ((unsigned)gx < W && (unsigned)gy < H) g = gray[gy * W + gx];
        sg[r][c] = g;
    }
    __syncthreads();
    if (t < NVT) {
        int c = t % CIN, r0 = (t / CIN) * 2;
        float2 acc[2];
        acc[0] = make_float2(0.f, 0.f); acc[1] = acc[0];
        #pragma unroll
        for (int s = 0; s < 22; ++s) {
            float g = sg[r0 + s][c];
            if (s <= 20) { float wg_ = wu.w[s] * g; acc[0].x += wg_; acc[0].y = fmaf(wg_, g, acc[0].y); }
            if (s >= 1)  { float wg_ = wu.w[s-1] * g; acc[1].x += wg_; acc[1].y = fmaf(wg_, g, acc[1].y); }
        }
        ii[r0][c] = acc[0]; ii[r0 + 1][c] = acc[1];
    }
    __syncthreads();
    int row = t >> 5, col = t & 31;
    float2 A = make_float2(0.f, 0.f);
    #pragma unroll
    for (int d = 0; d < KS; ++d) {
        float2 v = ii[row][col + d];
        A.x = fmaf(wu.w[d], v.x, A.x);
        A.y = fmaf(wu.w[d], v.y, A.y);
    }
    int py = y0 + row, px = x0 + col;
    int p = py * W + px;
    float gc = sg[row + RAD][col + RAD];
    float mI = A.x - c0u * gc;
    float mII = A.y - c0u * gc * gc;
    float iv = 1.f / ((mII - mI * mI) + CRF_EPS);
    float N = Su[px] * Su[py] - c0u;
    float av = mI * (1.f - N) * iv;
    float bv = N - av * mI;
    mean_I[p] = mI; inv_var[p] = iv; a1b1[p] = make_float2(av, bv);
}

// fused 2D conv of a1b1 -> inv_bilateral_norm
__global__ __launch_bounds__(256, 4) void k_s2(const float2* __restrict__ a1b1,
        const float* __restrict__ gray, float* __restrict__ inv_bn,
        W21 wu, float c0u) {
    __shared__ float2 s2[RIN][CIN];     // 11648 B
    __shared__ float2 ii[TY][CIN];      //  3328 B
    int L = swz(blockIdx.x, NBLK);
    int x0 = (L & (GX - 1)) * TX, y0 = (L >> 4) * TY;
    int t = threadIdx.x;
    for (int i = t; i < RIN * CIN; i += 256) {
        int r = i / CIN, c = i - r * CIN;
        int gx = x0 + c - RAD, gy = y0 + r - RAD;
        float2 v = make_float2(0.f, 0.f);
        if ((unsigned)gx < W && (unsigned)gy < H) v = a1b1[gy * W + gx];
        s2[r][c] = v;
    }
    __syncthreads();
    if (t < NVT) {
        int c = t % CIN, r0 = (t / CIN) * 2;
        float2 acc[2];
        acc[0] = make_float2(0.f, 0.f); acc[1] = acc[0];
        #pragma unroll
        for (int s = 0; s < 22; ++s) {
            float2 v = s2[r0 + s][c];
            if (s <= 20) { acc[0].x = fmaf(wu.w[s], v.x, acc[0].x); acc[0].y = fmaf(wu.w[s], v.y, acc[0].y); }
            if (s >= 1)  { acc[1].x = fmaf(wu.w[s-1], v.x, acc[1].x); acc[1].y = fmaf(wu.w[s-1], v.y, acc[1].y); }
        }
        ii[r0][c] = acc[0]; ii[r0 + 1][c] = acc[1];
    }
    __syncthreads();
    int row = t >> 5, col = t & 31;
    float2 A = make_float2(0.f, 0.f);
    #pragma unroll
    for (int d = 0; d < KS; ++d) {
        float2 v = ii[row][col + d];
        A.x = fmaf(wu.w[d], v.x, A.x);
        A.y = fmaf(wu.w[d], v.y, A.y);
    }
    int p = (y0 + row) * W + x0 + col;
    float2 cen = s2[row + RAD][col + RAD];
    float va = A.x - c0u * cen.x;
    float vb = A.y - c0u * cen.y;
    inv_bn[p] = 1.f / (va * gray[p] + vb);
}

// ---- iteration kernels ----

// F1: Q -> a, b, partial.  Stage Q+gray; V-conv (3 planes, 2 rows/thread,
// results held in regs); alias i0/i1 into the staging buffer; H-conv
// (1 output/thread, all 256 threads); pointwise with prefetched globals.
__global__ __launch_bounds__(256, 4) void k_f1(const float4* __restrict__ Q,
        const float* __restrict__ gray, const float* __restrict__ mean_I,
        const float* __restrict__ inv_var, const float* __restrict__ Sg,
        const float4* __restrict__ unary, float4* __restrict__ a_out,
        float4* __restrict__ b_out, float4* __restrict__ partial,
        W21 wg, W21 wu, float c0g, float c0u) {
    // layout: sQ [RIN][CIN]f4 (23296) | sG [RIN][CIN]f (5824) | i2 [TY][CIN]f4 (6656)
    // after V-phase, i0/i1 ([TY][CIN]f4, 6656 each) alias the sQ region.
    __shared__ __align__(16) char smem[23296 + 5824 + 6656];
    float4* sQ = (float4*)smem;
    float*  sG = (float*)(smem + 23296);
    float4* i2 = (float4*)(smem + 23296 + 5824);
    float4* i0 = (float4*)smem;
    float4* i1 = (float4*)(smem + 6656);
    int L = swz(blockIdx.x, NBLK);
    int x0 = (L & (GX - 1)) * TX, y0 = (L >> 4) * TY;
    int t = threadIdx.x;
    for (int i = t; i < RIN * CIN; i += 256) {
        int r = i / CIN, c = i - r * CIN;
        int gx = x0 + c - RAD, gy = y0 + r - RAD;
        float4 q = f4(0.f, 0.f, 0.f, 0.f); float g = 0.f;
        if ((unsigned)gx < W && (unsigned)gy < H) {
            int p = gy * W + gx; q = Q[p]; g = gray[p];
        }
        sQ[i] = q; sG[i] = g;
    }
    __syncthreads();
    // prefetch per-output globals + extract centers (sQ still intact)
    int row = t >> 5, col = t & 31;
    int py = y0 + row, px = x0 + col;
    int p = py * W + px;
    float mI = mean_I[p], iv = inv_var[p];
    float4 u = unary[p];
    float sgx = Sg[px], sgy = Sg[py];
    float4 Qc = sQ[(row + RAD) * CIN + col + RAD];
    float  gc = sG[(row + RAD) * CIN + col + RAD];
    // V-phase: 2 output rows per thread, results in registers
    float4 a0[2], a1[2], a2[2];
    int vc = t % CIN, vr0 = (t / CIN) * 2;
    if (t < NVT) {
        #pragma unroll
        for (int j = 0; j < 2; ++j) { a0[j] = f4(0,0,0,0); a1[j] = a0[j]; a2[j] = a0[j]; }
        #pragma unroll
        for (int s = 0; s < 22; ++s) {
            float4 q = sQ[(vr0 + s) * CIN + vc];
            float g = sG[(vr0 + s) * CIN + vc];
            float4 gq = f4(g * q.x, g * q.y, g * q.z, g * q.w);
            if (s <= 20) {
                a0[0] = fma4(wg.w[s], q, a0[0]);
                a1[0] = fma4(wu.w[s], q, a1[0]);
                a2[0] = fma4(wu.w[s], gq, a2[0]);
            }
            if (s >= 1) {
                a0[1] = fma4(wg.w[s-1], q, a0[1]);
                a1[1] = fma4(wu.w[s-1], q, a1[1]);
                a2[1] = fma4(wu.w[s-1], gq, a2[1]);
            }
        }
    }
    __syncthreads();     // all sQ reads done; safe to overwrite via i0/i1
    if (t < NVT) {
        #pragma unroll
        for (int j = 0; j < 2; ++j) {
            i0[(vr0 + j) * CIN + vc] = a0[j];
            i1[(vr0 + j) * CIN + vc] = a1[j];
            i2[(vr0 + j) * CIN + vc] = a2[j];
        }
    }
    __syncthreads();
    // H-phase: 1 output/thread
    float4 A0 = f4(0,0,0,0), A1 = A0, A2 = A0;
    #pragma unroll
    for (int d = 0; d < KS; ++d) {
        A0 = fma4(wg.w[d], i0[row * CIN + col + d], A0);
        A1 = fma4(wu.w[d], i1[row * CIN + col + d], A1);
        A2 = fma4(wu.w[d], i2[row * CIN + col + d], A2);
    }
    float4 g4  = fma4(-c0g, Qc, A0);
    float4 m4  = fma4(-c0u, Qc, A1);
    float4 mi4 = fma4(-c0u * gc, Qc, A2);
    float4 a, b;
    a.x = (mi4.x - mI * m4.x) * iv; a.y = (mi4.y - mI * m4.y) * iv;
    a.z = (mi4.z - mI * m4.z) * iv; a.w = (mi4.w - mI * m4.w) * iv;
    b.x = m4.x - a.x * mI; b.y = m4.y - a.y * mI;
    b.z = m4.z - a.z * mI; b.w = m4.w - a.w * mI;
    float s3 = 3.f / (sgx * sgy - c0g);
    float4 part = f4(fmaf(s3, g4.x, -u.x), fmaf(s3, g4.y, -u.y),
                     fmaf(s3, g4.z, -u.z), fmaf(s3, g4.w, -u.w));
    a_out[p] = a; b_out[p] = b; partial[p] = part;
}

// F2: a,b -> message + softmax -> Qout.  Sequential a/b phases with
// register-held V results; ib aliases the staging buffer.
__global__ __launch_bounds__(256, 4) void k_f2(const float4* __restrict__ A,
        const float4* __restrict__ B, const float4* __restrict__ partial,
        const float* __restrict__ gray, const float* __restrict__ inv_bn,
        float4* __restrict__ Qout, W21 wu, float c0u) {
    // layout: sT [RIN][CIN]f4 (23296) | ia [TY][CIN]f4 (6656); ib aliases sT.
    __shared__ __align__(16) char smem[23296 + 6656];
    float4* sT = (float4*)smem;
    float4* ia = (float4*)(smem + 23296);
    float4* ib = (float4*)smem;
    int L = swz(blockIdx.x, NBLK);
    int x0 = (L & (GX - 1)) * TX, y0 = (L >> 4) * TY;
    int t = threadIdx.x;
    int row = t >> 5, col = t & 31;
    int py = y0 + row, px = x0 + col;
    int p = py * W + px;
    int vc = t % CIN, vr0 = (t / CIN) * 2;
    // prefetch per-output globals
    float gv = gray[p];
    float ibn = 10.f * inv_bn[p];
    float4 part = partial[p];
    // --- phase A ---
    for (int i = t; i < RIN * CIN; i += 256) {
        int r = i / CIN, c = i - r * CIN;
        int gx = x0 + c - RAD, gy = y0 + r - RAD;
        float4 v = f4(0.f, 0.f, 0.f, 0.f);
        if ((unsigned)gx < W && (unsigned)gy < H) v = A[gy * W + gx];
        sT[i] = v;
    }
    __syncthreads();
    float4 Ac = sT[(row + RAD) * CIN + col + RAD];
    float4 va[2];
    va[0] = f4(0,0,0,0); va[1] = va[0];
    if (t < NVT) {
        #pragma unroll
        for (int s = 0; s < 22; ++s) {
            float4 v = sT[(vr0 + s) * CIN + vc];
            if (s <= 20) va[0] = fma4(wu.w[s], v, va[0]);
            if (s >= 1)  va[1] = fma4(wu.w[s-1], v, va[1]);
        }
        ia[vr0 * CIN + vc] = va[0];         // ia is a separate region
        ia[(vr0 + 1) * CIN + vc] = va[1];
    }
    __syncthreads();     // A reads + ia writes done
    // --- phase B ---
    for (int i = t; i < RIN * CIN; i += 256) {
        int r = i / CIN, c = i - r * CIN;
        int gx = x0 + c - RAD, gy = y0 + r - RAD;
        float4 v = f4(0.f, 0.f, 0.f, 0.f);
        if ((unsigned)gx < W && (unsigned)gy < H) v = B[gy * W + gx];
        sT[i] = v;
    }
    __syncthreads();
    float4 Bc = sT[(row + RAD) * CIN + col + RAD];
    float4 vb[2];
    vb[0] = f4(0,0,0,0); vb[1] = vb[0];
    if (t < NVT) {
        #pragma unroll
        for (int s = 0; s < 22; ++s) {
            float4 v = sT[(vr0 + s) * CIN + vc];
            if (s <= 20) vb[0] = fma4(wu.w[s], v, vb[0]);
            if (s >= 1)  vb[1] = fma4(wu.w[s-1], v, vb[1]);
        }
    }
    __syncthreads();     // B reads done; safe to overwrite sT via ib
    if (t < NVT) {
        ib[vr0 * CIN + vc] = vb[0];
        ib[(vr0 + 1) * CIN + vc] = vb[1];
    }
    __syncthreads();
    // --- H-phase + message + softmax ---
    float4 VA = f4(0,0,0,0), VB = VA;
    #pragma unroll
    for (int d = 0; d < KS; ++d) {
        VA = fma4(wu.w[d], ia[row * CIN + col + d], VA);
        VB = fma4(wu.w[d], ib[row * CIN + col + d], VB);
    }
    float4 a4 = fma4(-c0u, Ac, VA);
    float4 b4 = fma4(-c0u, Bc, VB);
    float lx = fmaf(fmaf(a4.x, gv, b4.x), ibn, part.x);
    float ly = fmaf(fmaf(a4.y, gv, b4.y), ibn, part.y);
    float lz = fmaf(fmaf(a4.z, gv, b4.z), ibn, part.z);
    float lw = fmaf(fmaf(a4.w, gv, b4.w), ibn, part.w);
    float m = fmaxf(fmaxf(lx, ly), fmaxf(lz, lw));
    float ex = expf(lx - m), ey = expf(ly - m), ez = expf(lz - m), ew = expf(lw - m);
    float inv = 1.f / (ex + ey + ez + ew);
    Qout[p] = f4(ex * inv, ey * inv, ez * inv, ew * inv);
}

// ---- host ----

static void make_w_host(double theta, W21* w, float* c0) {
    double tmp[KS], s = 0.0;
    for (int d = -RAD; d <= RAD; ++d) {
        double v = exp(-(double)(d * d) / (2.0 * theta * theta));
        tmp[d + RAD] = v; s += v;
    }
    for (int i = 0; i < KS; ++i) w->w[i] = (float)(tmp[i] / s);
    *c0 = (float)(1.0 / (s * s));   // normalized 2D center weight
}

extern "C" void kernel_launch(void* const* d_in, const int* in_sizes, int n_in,
                              void* d_out, int out_size, void* d_ws, size_t ws_size,
                              hipStream_t stream) {
    const float4* unary = (const float4*)d_in[0];
    const float* image = (const float*)d_in[1];
    float* wsf = (float*)d_ws;

    float*  gray    = wsf;
    float*  mean_I  = wsf + 262144;
    float*  inv_var = wsf + 524288;
    float2* a1b1    = (float2*)(wsf + 786432);
    float*  inv_bn  = wsf + 1310720;
    float*  Sg      = wsf + 1572864;
    float*  Su      = wsf + 1573376;
    float4* Q       = (float4*)(wsf + 1573888);
    float4* partial = (float4*)(wsf + 2622464);
    float4* a_arr   = (float4*)(wsf + 3671040);
    float4* b_arr   = (float4*)(wsf + 4719616);

    W21 wg, wu; float c0g, c0u;
    make_w_host(2.5, &wg, &c0g);
    make_w_host(10.0 / 3.0, &wu, &c0u);

    dim3 bl(256), grEl(NPIX / 256), grT(NBLK);

    k_init<<<grEl, bl, 0, stream>>>(image, unary, gray, Q, Sg, Su, wg, wu);
    k_s1<<<grT, bl, 0, stream>>>(gray, Su, mean_I, inv_var, a1b1, wu, c0u);
    k_s2<<<grT, bl, 0, stream>>>(a1b1, gray, inv_bn, wu, c0u);

    for (int it = 0; it < 5; ++it) {
        k_f1<<<grT, bl, 0, stream>>>((const float4*)Q, gray, mean_I, inv_var, Sg,
                                     unary, a_arr, b_arr, partial, wg, wu, c0g, c0u);
        float4* qdst = (it == 4) ? (float4*)d_out : Q;
        k_f2<<<grT, bl, 0, stream>>>(a_arr, b_arr, partial, gray, inv_bn, qdst,
                                     wu, c0u);
    }
}

// Round 7
// 170.468 us; speedup vs baseline: 1.1884x; 1.0176x over previous
//
#include <hip/hip_runtime.h>
#include <hip/hip_cooperative_groups.h>
#include <math.h>

namespace cg = cooperative_groups;

#define W 512
#define H 512
#define NPIX (W*H)
#define RAD 10
#define KS 21
#define CRF_EPS 1e-4f

// tile geometry: TX x TY outputs per block, halo RAD each side
#define TX 32
#define TY 8
#define CIN (TX + 2*RAD)   // 52
#define RIN (TY + 2*RAD)   // 28
#define GX (W / TX)        // 16
#define GY (H / TY)        // 64
#define NBLK (GX*GY)       // 1024 blocks
#define NVT (CIN * 4)      // 208 V-phase threads (2 output rows each)

// Cooperative-kernel LDS (29,952 B => 5 blocks/CU LDS capacity):
//  region0 [0, 23296): staging sQ/sT/s2t; post-V aliases i0 [0,6656),
//                      i1 [6656,13312), ib [0,6656); s1 V-out ii0 (3328)
//  region1 [23296, 29952): sG gray tile (5824) during f1 V / i2 after;
//                          ia in f2; ii1 in s2
#define SM_BYTES 29952
#define OFF_R1 23296

struct W21 { float w[KS]; };

struct Params {
    const float4* unary;
    const float*  image;
    float*  gray;
    float4* Q;
    float2* a1b1;
    float4* a_arr;
    float4* b_arr;
    float4* Qfinal;
    W21 wg, wu;
    float c0g, c0u;
};

__device__ __forceinline__ float4 f4(float x, float y, float z, float w_) {
    return make_float4(x, y, z, w_);
}
__device__ __forceinline__ float4 fma4(float s, float4 a, float4 acc) {
    acc.x = fmaf(s, a.x, acc.x); acc.y = fmaf(s, a.y, acc.y);
    acc.z = fmaf(s, a.z, acc.z); acc.w = fmaf(s, a.w, acc.w);
    return acc;
}
__device__ __forceinline__ int swz(int b, int N) {
    return (b & 7) * (N >> 3) + (b >> 3);
}

// ======================= cooperative single-kernel path ====================

__global__ __launch_bounds__(256, 5) void k_crf(Params P) {
    cg::grid_group grid = cg::this_grid();
    __shared__ __align__(16) char smem[SM_BYTES];
    float4* sQ  = (float4*)smem;                    // f1/f2 staging
    float2* s2t = (float2*)smem;                    // s2 staging
    float2* ii0 = (float2*)smem;                    // s1 V-out (region0)
    float*  sG  = (float*)(smem + OFF_R1);          // gray tile (region1)
    float2* ii1 = (float2*)(smem + OFF_R1);         // s2 V-out (region1)
    float4* i0  = (float4*)smem;                    // f1 post-V aliases
    float4* i1  = (float4*)(smem + 6656);
    float4* i2  = (float4*)(smem + OFF_R1);
    float4* ia  = (float4*)(smem + OFF_R1);         // f2 V-out A
    float4* ib  = (float4*)smem;                    // f2 V-out B

    int t = threadIdx.x;
    int L = swz(blockIdx.x, NBLK);
    int x0 = (L & (GX - 1)) * TX, y0 = (L >> 4) * TY;
    int row = t >> 5, col = t & 31;
    int py = y0 + row, px = x0 + col;
    int p = py * W + px;
    int vc = t % CIN, vr0 = (t / CIN) * 2;
    int cidx = (row + RAD) * CIN + col + RAD;

    // ---- phase 0: gray + softmax(-unary), linear coalesced ----
    {
        int pi = blockIdx.x * 256 + t;
        float r = P.image[3 * pi], g = P.image[3 * pi + 1], b = P.image[3 * pi + 2];
        P.gray[pi] = 0.2989f * r + 0.5870f * g + 0.1140f * b;
        float4 u0 = P.unary[pi];
        float mn = fminf(fminf(u0.x, u0.y), fminf(u0.z, u0.w));
        float ex = expf(mn - u0.x), ey = expf(mn - u0.y);
        float ez = expf(mn - u0.z), ew = expf(mn - u0.w);
        float inv = 1.f / (ex + ey + ez + ew);
        P.Q[pi] = f4(ex * inv, ey * inv, ez * inv, ew * inv);
    }
    float4 u = P.unary[p];
    float Sgx = 0.f, Sgy = 0.f, Sux = 0.f, Suy = 0.f;
    #pragma unroll
    for (int d = -RAD; d <= RAD; ++d) {
        int xx = px + d, yy = py + d;
        if (xx >= 0 && xx < W) { Sgx += P.wg.w[d + RAD]; Sux += P.wu.w[d + RAD]; }
        if (yy >= 0 && yy < H) { Sgy += P.wg.w[d + RAD]; Suy += P.wu.w[d + RAD]; }
    }
    float s3 = 3.f / (Sgx * Sgy - P.c0g);          // SPATIAL_COMPAT / spatial_norm
    grid.sync();

    // ---- s1: conv{gray, gray^2} -> mI, iv (regs); a1b1 -> global ----
    for (int i = t; i < RIN * CIN; i += 256) {
        int r = i / CIN, c = i - r * CIN;
        int gx = x0 + c - RAD, gy = y0 + r - RAD;
        float g = 0.f;
        if ((unsigned)gx < W && (unsigned)gy < H) g = P.gray[gy * W + gx];
        sG[i] = g;
    }
    __syncthreads();
    if (t < NVT) {
        float2 acc0 = make_float2(0.f, 0.f), acc1 = acc0;
        #pragma unroll
        for (int s = 0; s < 22; ++s) {
            float g = sG[(vr0 + s) * CIN + vc];
            if (s <= 20) { float wgv = P.wu.w[s] * g; acc0.x += wgv; acc0.y = fmaf(wgv, g, acc0.y); }
            if (s >= 1)  { float wgv = P.wu.w[s-1] * g; acc1.x += wgv; acc1.y = fmaf(wgv, g, acc1.y); }
        }
        ii0[vr0 * CIN + vc] = acc0;                // region0 (free during s1)
        ii0[(vr0 + 1) * CIN + vc] = acc1;
    }
    __syncthreads();
    float gv = sG[cidx];                           // persists in reg
    float mI, iv, ibn;
    {
        float2 A = make_float2(0.f, 0.f);
        #pragma unroll
        for (int d = 0; d < KS; ++d) {
            float2 v = ii0[row * CIN + col + d];
            A.x = fmaf(P.wu.w[d], v.x, A.x);
            A.y = fmaf(P.wu.w[d], v.y, A.y);
        }
        mI = A.x - P.c0u * gv;
        float mII = A.y - P.c0u * gv * gv;
        iv = 1.f / ((mII - mI * mI) + CRF_EPS);
        float N = Sux * Suy - P.c0u;               // gf(ones)
        float a1v = mI * (1.f - N) * iv;
        float b1v = N - a1v * mI;
        P.a1b1[p] = make_float2(a1v, b1v);
    }
    grid.sync();

    // ---- s2: conv a1b1 -> inv_bn (reg) ----
    for (int i = t; i < RIN * CIN; i += 256) {
        int r = i / CIN, c = i - r * CIN;
        int gx = x0 + c - RAD, gy = y0 + r - RAD;
        float2 v = make_float2(0.f, 0.f);
        if ((unsigned)gx < W && (unsigned)gy < H) v = P.a1b1[gy * W + gx];
        s2t[i] = v;
    }
    __syncthreads();
    if (t < NVT) {
        float2 acc0 = make_float2(0.f, 0.f), acc1 = acc0;
        #pragma unroll
        for (int s = 0; s < 22; ++s) {
            float2 v = s2t[(vr0 + s) * CIN + vc];
            if (s <= 20) { acc0.x = fmaf(P.wu.w[s], v.x, acc0.x); acc0.y = fmaf(P.wu.w[s], v.y, acc0.y); }
            if (s >= 1)  { acc1.x = fmaf(P.wu.w[s-1], v.x, acc1.x); acc1.y = fmaf(P.wu.w[s-1], v.y, acc1.y); }
        }
        ii1[vr0 * CIN + vc] = acc0;                // region1 (sG dead; gv in reg)
        ii1[(vr0 + 1) * CIN + vc] = acc1;
    }
    __syncthreads();
    {
        float2 A = make_float2(0.f, 0.f);
        #pragma unroll
        for (int d = 0; d < KS; ++d) {
            float2 v = ii1[row * CIN + col + d];
            A.x = fmaf(P.wu.w[d], v.x, A.x);
            A.y = fmaf(P.wu.w[d], v.y, A.y);
        }
        float2 cen = s2t[cidx];
        float va = A.x - P.c0u * cen.x;
        float vb = A.y - P.c0u * cen.y;
        ibn = 10.f / (va * gv + vb);               // BILATERAL_COMPAT / norm
    }

    // ---- 5 mean-field iterations ----
    float px_part, py_part, pz_part, pw_part;
    for (int it = 0; it < 5; ++it) {
        // === f1 ===
        __syncthreads();                           // region0/1 reads done
        for (int i = t; i < RIN * CIN; i += 256) {
            int r = i / CIN, c = i - r * CIN;
            int gx = x0 + c - RAD, gy = y0 + r - RAD;
            float4 q = f4(0.f, 0.f, 0.f, 0.f); float g = 0.f;
            if ((unsigned)gx < W && (unsigned)gy < H) {
                int pp = gy * W + gx; q = P.Q[pp]; g = P.gray[pp];
            }
            sQ[i] = q; sG[i] = g;                  // re-stage gray each iter
        }
        __syncthreads();
        float4 Qc = sQ[cidx];
        float4 a0[2], a1r[2], a2[2];
        if (t < NVT) {
            #pragma unroll
            for (int j = 0; j < 2; ++j) { a0[j] = f4(0,0,0,0); a1r[j] = a0[j]; a2[j] = a0[j]; }
            #pragma unroll
            for (int s = 0; s < 22; ++s) {
                float4 q = sQ[(vr0 + s) * CIN + vc];
                float g = sG[(vr0 + s) * CIN + vc];
                float4 gq = f4(g * q.x, g * q.y, g * q.z, g * q.w);
                if (s <= 20) {
                    a0[0]  = fma4(P.wg.w[s], q, a0[0]);
                    a1r[0] = fma4(P.wu.w[s], q, a1r[0]);
                    a2[0]  = fma4(P.wu.w[s], gq, a2[0]);
                }
                if (s >= 1) {
                    a0[1]  = fma4(P.wg.w[s-1], q, a0[1]);
                    a1r[1] = fma4(P.wu.w[s-1], q, a1r[1]);
                    a2[1]  = fma4(P.wu.w[s-1], gq, a2[1]);
                }
            }
        }
        __syncthreads();                           // sQ+sG reads done
        if (t < NVT) {
            #pragma unroll
            for (int j = 0; j < 2; ++j) {
                i0[(vr0 + j) * CIN + vc] = a0[j];
                i1[(vr0 + j) * CIN + vc] = a1r[j];
                i2[(vr0 + j) * CIN + vc] = a2[j];   // overwrites sG (dead)
            }
        }
        __syncthreads();
        {
            float4 A0 = f4(0,0,0,0), A1 = A0, A2 = A0;
            #pragma unroll
            for (int d = 0; d < KS; ++d) {
                A0 = fma4(P.wg.w[d], i0[row * CIN + col + d], A0);
                A1 = fma4(P.wu.w[d], i1[row * CIN + col + d], A1);
                A2 = fma4(P.wu.w[d], i2[row * CIN + col + d], A2);
            }
            float4 g4  = fma4(-P.c0g, Qc, A0);
            float4 m4  = fma4(-P.c0u, Qc, A1);
            float4 mi4 = fma4(-P.c0u * gv, Qc, A2);
            float4 a, b;
            a.x = (mi4.x - mI * m4.x) * iv; a.y = (mi4.y - mI * m4.y) * iv;
            a.z = (mi4.z - mI * m4.z) * iv; a.w = (mi4.w - mI * m4.w) * iv;
            b.x = m4.x - a.x * mI; b.y = m4.y - a.y * mI;
            b.z = m4.z - a.z * mI; b.w = m4.w - a.w * mI;
            px_part = fmaf(s3, g4.x, -u.x); py_part = fmaf(s3, g4.y, -u.y);
            pz_part = fmaf(s3, g4.z, -u.z); pw_part = fmaf(s3, g4.w, -u.w);
            P.a_arr[p] = a; P.b_arr[p] = b;
        }
        grid.sync();

        // === f2 ===
        for (int i = t; i < RIN * CIN; i += 256) {
            int r = i / CIN, c = i - r * CIN;
            int gx = x0 + c - RAD, gy = y0 + r - RAD;
            float4 v = f4(0.f, 0.f, 0.f, 0.f);
            if ((unsigned)gx < W && (unsigned)gy < H) v = P.a_arr[gy * W + gx];
            sQ[i] = v;
        }
        __syncthreads();
        float4 Ac = sQ[cidx];
        if (t < NVT) {
            float4 va0 = f4(0,0,0,0), va1 = va0;
            #pragma unroll
            for (int s = 0; s < 22; ++s) {
                float4 v = sQ[(vr0 + s) * CIN + vc];
                if (s <= 20) va0 = fma4(P.wu.w[s], v, va0);
                if (s >= 1)  va1 = fma4(P.wu.w[s-1], v, va1);
            }
            ia[vr0 * CIN + vc] = va0;              // region1, no clobber of sQ
            ia[(vr0 + 1) * CIN + vc] = va1;
        }
        __syncthreads();                           // sQ(A) reads + ia writes done
        for (int i = t; i < RIN * CIN; i += 256) {
            int r = i / CIN, c = i - r * CIN;
            int gx = x0 + c - RAD, gy = y0 + r - RAD;
            float4 v = f4(0.f, 0.f, 0.f, 0.f);
            if ((unsigned)gx < W && (unsigned)gy < H) v = P.b_arr[gy * W + gx];
            sQ[i] = v;
        }
        __syncthreads();
        float4 Bc = sQ[cidx];
        float4 vb0 = f4(0,0,0,0), vb1 = vb0;
        if (t < NVT) {
            #pragma unroll
            for (int s = 0; s < 22; ++s) {
                float4 v = sQ[(vr0 + s) * CIN + vc];
                if (s <= 20) vb0 = fma4(P.wu.w[s], v, vb0);
                if (s >= 1)  vb1 = fma4(P.wu.w[s-1], v, vb1);
            }
        }
        __syncthreads();                           // sQ(B) reads done
        if (t < NVT) {
            ib[vr0 * CIN + vc] = vb0;              // overwrite region0
            ib[(vr0 + 1) * CIN + vc] = vb1;
        }
        __syncthreads();
        {
            float4 VA = f4(0,0,0,0), VB = VA;
            #pragma unroll
            for (int d = 0; d < KS; ++d) {
                VA = fma4(P.wu.w[d], ia[row * CIN + col + d], VA);
                VB = fma4(P.wu.w[d], ib[row * CIN + col + d], VB);
            }
            float4 a4 = fma4(-P.c0u, Ac, VA);
            float4 b4 = fma4(-P.c0u, Bc, VB);
            float lx = fmaf(fmaf(a4.x, gv, b4.x), ibn, px_part);
            float ly = fmaf(fmaf(a4.y, gv, b4.y), ibn, py_part);
            float lz = fmaf(fmaf(a4.z, gv, b4.z), ibn, pz_part);
            float lw = fmaf(fmaf(a4.w, gv, b4.w), ibn, pw_part);
            float m = fmaxf(fmaxf(lx, ly), fmaxf(lz, lw));
            float ex = expf(lx - m), ey = expf(ly - m);
            float ez = expf(lz - m), ew = expf(lw - m);
            float inv = 1.f / (ex + ey + ez + ew);
            float4 qn = f4(ex * inv, ey * inv, ez * inv, ew * inv);
            if (it == 4) P.Qfinal[p] = qn;
            else         P.Q[p] = qn;
        }
        if (it < 4) grid.sync();
    }
}

// ===================== fallback: proven round-5 multi-dispatch ==============

__global__ __launch_bounds__(256) void fb_init(const float* __restrict__ img,
        const float4* __restrict__ unary, float* __restrict__ gray,
        float4* __restrict__ Q, float* __restrict__ Sg, float* __restrict__ Su,
        W21 wg, W21 wu) {
    int t = threadIdx.x;
    if (blockIdx.x < 2) {
        int x = blockIdx.x * 256 + t;
        float sg = 0.f, su = 0.f;
        #pragma unroll
        for (int d = -RAD; d <= RAD; ++d) {
            int xx = x + d;
            if (xx >= 0 && xx < W) { sg += wg.w[d + RAD]; su += wu.w[d + RAD]; }
        }
        Sg[x] = sg; Su[x] = su;
    }
    int b = swz(blockIdx.x, NPIX / 256);
    int p = b * 256 + t;
    float r = img[3 * p], g = img[3 * p + 1], bch = img[3 * p + 2];
    gray[p] = 0.2989f * r + 0.5870f * g + 0.1140f * bch;
    float4 u = unary[p];
    float mn = fminf(fminf(u.x, u.y), fminf(u.z, u.w));
    float ex = expf(mn - u.x), ey = expf(mn - u.y), ez = expf(mn - u.z), ew = expf(mn - u.w);
    float inv = 1.f / (ex + ey + ez + ew);
    Q[p] = f4(ex * inv, ey * inv, ez * inv, ew * inv);
}

__global__ __launch_bounds__(256, 4) void fb_s1(const float* __restrict__ gray,
        const float* __restrict__ Su, float* __restrict__ mean_I,
        float* __restrict__ inv_var, float2* __restrict__ a1b1,
        W21 wu, float c0u) {
    __shared__ float  sg[RIN][CIN];
    __shared__ float2 ii[TY][CIN];
    int L = swz(blockIdx.x, NBLK);
    int x0 = (L & (GX - 1)) * TX, y0 = (L >> 4) * TY;
    int t = threadIdx.x;
    for (int i = t; i < RIN * CIN; i += 256) {
        int r = i / CIN, c = i - r * CIN;
        int gx = x0 + c - RAD, gy = y0 + r - RAD;
        float g = 0.f;
        if ((unsigned)gx < W && (unsigned)gy < H) g = gray[gy * W + gx];
        sg[r][c] = g;
    }
    __syncthreads();
    if (t < NVT) {
        int c = t % CIN, r0 = (t / CIN) * 2;
        float2 acc0 = make_float2(0.f, 0.f), acc1 = acc0;
        #pragma unroll
        for (int s = 0; s < 22; ++s) {
            float g = sg[r0 + s][c];
            if (s <= 20) { float wgv = wu.w[s] * g; acc0.x += wgv; acc0.y = fmaf(wgv, g, acc0.y); }
            if (s >= 1)  { float wgv = wu.w[s-1] * g; acc1.x += wgv; acc1.y = fmaf(wgv, g, acc1.y); }
        }
        ii[r0][c] = acc0; ii[r0 + 1][c] = acc1;
    }
    __syncthreads();
    int row = t >> 5, col = t & 31;
    float2 A = make_float2(0.f, 0.f);
    #pragma unroll
    for (int d = 0; d < KS; ++d) {
        float2 v = ii[row][col + d];
        A.x = fmaf(wu.w[d], v.x, A.x);
        A.y = fmaf(wu.w[d], v.y, A.y);
    }
    int py = y0 + row, px = x0 + col;
    int p = py * W + px;
    float gc = sg[row + RAD][col + RAD];
    float mI = A.x - c0u * gc;
    float mII = A.y - c0u * gc * gc;
    float iv = 1.f / ((mII - mI * mI) + CRF_EPS);
    float N = Su[px] * Su[py] - c0u;
    float av = mI * (1.f - N) * iv;
    float bv = N - av * mI;
    mean_I[p] = mI; inv_var[p] = iv; a1b1[p] = make_float2(av, bv);
}

__global__ __launch_bounds__(256, 4) void fb_s2(const float2* __restrict__ a1b1,
        const float* __restrict__ gray, float* __restrict__ inv_bn,
        W21 wu, float c0u) {
    __shared__ float2 s2[RIN][CIN];
    __shared__ float2 ii[TY][CIN];
    int L = swz(blockIdx.x, NBLK);
    int x0 = (L & (GX - 1)) * TX, y0 = (L >> 4) * TY;
    int t = threadIdx.x;
    for (int i = t; i < RIN * CIN; i += 256) {
        int r = i / CIN, c = i - r * CIN;
        int gx = x0 + c - RAD, gy = y0 + r - RAD;
        float2 v = make_float2(0.f, 0.f);
        if ((unsigned)gx < W && (unsigned)gy < H) v = a1b1[gy * W + gx];
        s2[r][c] = v;
    }
    __syncthreads();
    if (t < NVT) {
        int c = t % CIN, r0 = (t / CIN) * 2;
        float2 acc0 = make_float2(0.f, 0.f), acc1 = acc0;
        #pragma unroll
        for (int s = 0; s < 22; ++s) {
            float2 v = s2[r0 + s][c];
            if (s <= 20) { acc0.x = fmaf(wu.w[s], v.x, acc0.x); acc0.y = fmaf(wu.w[s], v.y, acc0.y); }
            if (s >= 1)  { acc1.x = fmaf(wu.w[s-1], v.x, acc1.x); acc1.y = fmaf(wu.w[s-1], v.y, acc1.y); }
        }
        ii[r0][c] = acc0; ii[r0 + 1][c] = acc1;
    }
    __syncthreads();
    int row = t >> 5, col = t & 31;
    float2 A = make_float2(0.f, 0.f);
    #pragma unroll
    for (int d = 0; d < KS; ++d) {
        float2 v = ii[row][col + d];
        A.x = fmaf(wu.w[d], v.x, A.x);
        A.y = fmaf(wu.w[d], v.y, A.y);
    }
    int p = (y0 + row) * W + x0 + col;
    float2 cen = s2[row + RAD][col + RAD];
    float va = A.x - c0u * cen.x;
    float vb = A.y - c0u * cen.y;
    inv_bn[p] = 1.f / (va * gray[p] + vb);
}

__global__ __launch_bounds__(256, 4) void fb_f1(const float4* __restrict__ Q,
        const float* __restrict__ gray, const float* __restrict__ mean_I,
        const float* __restrict__ inv_var, const float* __restrict__ Sg,
        const float4* __restrict__ unary, float4* __restrict__ a_out,
        float4* __restrict__ b_out, float4* __restrict__ partial,
        W21 wg, W21 wu, float c0g, float c0u) {
    __shared__ __align__(16) char smem[23296 + 5824 + 6656];
    float4* sQ = (float4*)smem;
    float*  sG = (float*)(smem + 23296);
    float4* i2 = (float4*)(smem + 23296 + 5824);
    float4* i0 = (float4*)smem;
    float4* i1 = (float4*)(smem + 6656);
    int L = swz(blockIdx.x, NBLK);
    int x0 = (L & (GX - 1)) * TX, y0 = (L >> 4) * TY;
    int t = threadIdx.x;
    for (int i = t; i < RIN * CIN; i += 256) {
        int r = i / CIN, c = i - r * CIN;
        int gx = x0 + c - RAD, gy = y0 + r - RAD;
        float4 q = f4(0.f, 0.f, 0.f, 0.f); float g = 0.f;
        if ((unsigned)gx < W && (unsigned)gy < H) {
            int p = gy * W + gx; q = Q[p]; g = gray[p];
        }
        sQ[i] = q; sG[i] = g;
    }
    __syncthreads();
    int row = t >> 5, col = t & 31;
    int py = y0 + row, px = x0 + col;
    int p = py * W + px;
    float mI = mean_I[p], iv = inv_var[p];
    float4 u = unary[p];
    float sgx = Sg[px], sgy = Sg[py];
    float4 Qc = sQ[(row + RAD) * CIN + col + RAD];
    float  gc = sG[(row + RAD) * CIN + col + RAD];
    float4 a0[2], a1[2], a2[2];
    int vc = t % CIN, vr0 = (t / CIN) * 2;
    if (t < NVT) {
        #pragma unroll
        for (int j = 0; j < 2; ++j) { a0[j] = f4(0,0,0,0); a1[j] = a0[j]; a2[j] = a0[j]; }
        #pragma unroll
        for (int s = 0; s < 22; ++s) {
            float4 q = sQ[(vr0 + s) * CIN + vc];
            float g = sG[(vr0 + s) * CIN + vc];
            float4 gq = f4(g * q.x, g * q.y, g * q.z, g * q.w);
            if (s <= 20) {
                a0[0] = fma4(wg.w[s], q, a0[0]);
                a1[0] = fma4(wu.w[s], q, a1[0]);
                a2[0] = fma4(wu.w[s], gq, a2[0]);
            }
            if (s >= 1) {
                a0[1] = fma4(wg.w[s-1], q, a0[1]);
                a1[1] = fma4(wu.w[s-1], q, a1[1]);
                a2[1] = fma4(wu.w[s-1], gq, a2[1]);
            }
        }
    }
    __syncthreads();
    if (t < NVT) {
        #pragma unroll
        for (int j = 0; j < 2; ++j) {
            i0[(vr0 + j) * CIN + vc] = a0[j];
            i1[(vr0 + j) * CIN + vc] = a1[j];
            i2[(vr0 + j) * CIN + vc] = a2[j];
        }
    }
    __syncthreads();
    float4 A0 = f4(0,0,0,0), A1 = A0, A2 = A0;
    #pragma unroll
    for (int d = 0; d < KS; ++d) {
        A0 = fma4(wg.w[d], i0[row * CIN + col + d], A0);
        A1 = fma4(wu.w[d], i1[row * CIN + col + d], A1);
        A2 = fma4(wu.w[d], i2[row * CIN + col + d], A2);
    }
    float4 g4  = fma4(-c0g, Qc, A0);
    float4 m4  = fma4(-c0u, Qc, A1);
    float4 mi4 = fma4(-c0u * gc, Qc, A2);
    float4 a, b;
    a.x = (mi4.x - mI * m4.x) * iv; a.y = (mi4.y - mI * m4.y) * iv;
    a.z = (mi4.z - mI * m4.z) * iv; a.w = (mi4.w - mI * m4.w) * iv;
    b.x = m4.x - a.x * mI; b.y = m4.y - a.y * mI;
    b.z = m4.z - a.z * mI; b.w = m4.w - a.w * mI;
    float s3 = 3.f / (sgx * sgy - c0g);
    float4 part = f4(fmaf(s3, g4.x, -u.x), fmaf(s3, g4.y, -u.y),
                     fmaf(s3, g4.z, -u.z), fmaf(s3, g4.w, -u.w));
    a_out[p] = a; b_out[p] = b; partial[p] = part;
}

__global__ __launch_bounds__(256, 4) void fb_f2(const float4* __restrict__ A,
        const float4* __restrict__ B, const float4* __restrict__ partial,
        const float* __restrict__ gray, const float* __restrict__ inv_bn,
        float4* __restrict__ Qout, W21 wu, float c0u) {
    __shared__ __align__(16) char smem[23296 + 6656];
    float4* sT = (float4*)smem;
    float4* ia = (float4*)(smem + 23296);
    float4* ib = (float4*)smem;
    int L = swz(blockIdx.x, NBLK);
    int x0 = (L & (GX - 1)) * TX, y0 = (L >> 4) * TY;
    int t = threadIdx.x;
    int row = t >> 5, col = t & 31;
    int py = y0 + row, px = x0 + col;
    int p = py * W + px;
    int vc = t % CIN, vr0 = (t / CIN) * 2;
    float gv = gray[p];
    float ibn = 10.f * inv_bn[p];
    float4 part = partial[p];
    for (int i = t; i < RIN * CIN; i += 256) {
        int r = i / CIN, c = i - r * CIN;
        int gx = x0 + c - RAD, gy = y0 + r - RAD;
        float4 v = f4(0.f, 0.f, 0.f, 0.f);
        if ((unsigned)gx < W && (unsigned)gy < H) v = A[gy * W + gx];
        sT[i] = v;
    }
    __syncthreads();
    float4 Ac = sT[(row + RAD) * CIN + col + RAD];
    float4 va0 = f4(0,0,0,0), va1 = va0;
    if (t < NVT) {
        #pragma unroll
        for (int s = 0; s < 22; ++s) {
            float4 v = sT[(vr0 + s) * CIN + vc];
            if (s <= 20) va0 = fma4(wu.w[s], v, va0);
            if (s >= 1)  va1 = fma4(wu.w[s-1], v, va1);
        }
        ia[vr0 * CIN + vc] = va0;
        ia[(vr0 + 1) * CIN + vc] = va1;
    }
    __syncthreads();
    for (int i = t; i < RIN * CIN; i += 256) {
        int r = i / CIN, c = i - r * CIN;
        int gx = x0 + c - RAD, gy = y0 + r - RAD;
        float4 v = f4(0.f, 0.f, 0.f, 0.f);
        if ((unsigned)gx < W && (unsigned)gy < H) v = B[gy * W + gx];
        sT[i] = v;
    }
    __syncthreads();
    float4 Bc = sT[(row + RAD) * CIN + col + RAD];
    float4 vb0 = f4(0,0,0,0), vb1 = vb0;
    if (t < NVT) {
        #pragma unroll
        for (int s = 0; s < 22; ++s) {
            float4 v = sT[(vr0 + s) * CIN + vc];
            if (s <= 20) vb0 = fma4(wu.w[s], v, vb0);
            if (s >= 1)  vb1 = fma4(wu.w[s-1], v, vb1);
        }
    }
    __syncthreads();
    if (t < NVT) {
        ib[vr0 * CIN + vc] = vb0;
        ib[(vr0 + 1) * CIN + vc] = vb1;
    }
    __syncthreads();
    float4 VA = f4(0,0,0,0), VB = VA;
    #pragma unroll
    for (int d = 0; d < KS; ++d) {
        VA = fma4(wu.w[d], ia[row * CIN + col + d], VA);
        VB = fma4(wu.w[d], ib[row * CIN + col + d], VB);
    }
    float4 a4 = fma4(-c0u, Ac, VA);
    float4 b4 = fma4(-c0u, Bc, VB);
    float lx = fmaf(fmaf(a4.x, gv, b4.x), ibn, part.x);
    float ly = fmaf(fmaf(a4.y, gv, b4.y), ibn, part.y);
    float lz = fmaf(fmaf(a4.z, gv, b4.z), ibn, part.z);
    float lw = fmaf(fmaf(a4.w, gv, b4.w), ibn, part.w);
    float m = fmaxf(fmaxf(lx, ly), fmaxf(lz, lw));
    float ex = expf(lx - m), ey = expf(ly - m), ez = expf(lz - m), ew = expf(lw - m);
    float inv = 1.f / (ex + ey + ez + ew);
    Qout[p] = f4(ex * inv, ey * inv, ez * inv, ew * inv);
}

// ---- host ----

static void make_w_host(double theta, W21* w, float* c0) {
    double tmp[KS], s = 0.0;
    for (int d = -RAD; d <= RAD; ++d) {
        double v = exp(-(double)(d * d) / (2.0 * theta * theta));
        tmp[d + RAD] = v; s += v;
    }
    for (int i = 0; i < KS; ++i) w->w[i] = (float)(tmp[i] / s);
    *c0 = (float)(1.0 / (s * s));   // normalized 2D center weight
}

extern "C" void kernel_launch(void* const* d_in, const int* in_sizes, int n_in,
                              void* d_out, int out_size, void* d_ws, size_t ws_size,
                              hipStream_t stream) {
    const float4* unary = (const float4*)d_in[0];
    const float* image = (const float*)d_in[1];
    float* wsf = (float*)d_ws;

    float*  gray    = wsf;
    float*  mean_I  = wsf + 262144;
    float*  inv_var = wsf + 524288;
    float2* a1b1    = (float2*)(wsf + 786432);
    float*  inv_bn  = wsf + 1310720;
    float*  Sg      = wsf + 1572864;
    float*  Su      = wsf + 1573376;
    float4* Q       = (float4*)(wsf + 1573888);
    float4* partial = (float4*)(wsf + 2622464);
    float4* a_arr   = (float4*)(wsf + 3671040);
    float4* b_arr   = (float4*)(wsf + 4719616);

    W21 wg, wu; float c0g, c0u;
    make_w_host(2.5, &wg, &c0g);
    make_w_host(10.0 / 3.0, &wu, &c0u);

    // deterministic cooperative-capacity pre-check (host-only, capture-safe)
    int dev = 0;
    (void)hipGetDevice(&dev);
    int coop = 0, nCU = 0, blkPerCU = 0;
    (void)hipDeviceGetAttribute(&coop, hipDeviceAttributeCooperativeLaunch, dev);
    (void)hipDeviceGetAttribute(&nCU, hipDeviceAttributeMultiprocessorCount, dev);
    (void)hipOccupancyMaxActiveBlocksPerMultiprocessor(&blkPerCU,
            (const void*)k_crf, 256, 0);
    bool useCoop = (coop != 0) && ((long)blkPerCU * nCU >= NBLK);

    hipError_t st = hipErrorUnknown;
    if (useCoop) {
        Params P;
        P.unary = unary; P.image = image; P.gray = gray; P.Q = Q;
        P.a1b1 = a1b1; P.a_arr = a_arr; P.b_arr = b_arr;
        P.Qfinal = (float4*)d_out;
        P.wg = wg; P.wu = wu; P.c0g = c0g; P.c0u = c0u;
        void* args[] = { &P };
        st = hipLaunchCooperativeKernel((const void*)k_crf, dim3(NBLK), dim3(256),
                                        args, 0, stream);
    }
    if (st != hipSuccess) {
        dim3 bl(256), grEl(NPIX / 256), grT(NBLK);
        fb_init<<<grEl, bl, 0, stream>>>(image, unary, gray, Q, Sg, Su, wg, wu);
        fb_s1<<<grT, bl, 0, stream>>>(gray, Su, mean_I, inv_var, a1b1, wu, c0u);
        fb_s2<<<grT, bl, 0, stream>>>(a1b1, gray, inv_bn, wu, c0u);
        for (int it = 0; it < 5; ++it) {
            fb_f1<<<grT, bl, 0, stream>>>(Q, gray, mean_I, inv_var, Sg,
                                          unary, a_arr, b_arr, partial, wg, wu, c0g, c0u);
            float4* qdst = (it == 4) ? (float4*)d_out : Q;
            fb_f2<<<grT, bl, 0, stream>>>(a_arr, b_arr, partial, gray, inv_bn, qdst,
                                          wu, c0u);
        }
    }
}